// Round 1
// baseline (1717.918 us; speedup 1.0000x reference)
//
#include <hip/hip_runtime.h>
#include <hip/hip_bf16.h>

namespace {

constexpr int N_NODES = 100000;
constexpr int N_EDGES = 600000;
constexpr int D_NODE  = 128;
constexpr int D_EDGE  = 128;
constexpr int D_HID   = 512;
constexpr int D_OUT   = 128;

// One thread per (edge, 4-float group). Coalesced float4 reads of edge
// features; 4 global f32 atomicAdds into agg[src].
__global__ void scatter_add_kernel(const float* __restrict__ ef,
                                   const int* __restrict__ src,
                                   float* __restrict__ agg) {
  long long idx = (long long)blockIdx.x * blockDim.x + threadIdx.x;
  constexpr long long total = (long long)N_EDGES * 32;
  if (idx >= total) return;
  const int e = (int)(idx >> 5);
  const int q = ((int)idx & 31) << 2;
  const float4 v = *reinterpret_cast<const float4*>(ef + (long long)e * D_EDGE + q);
  const int s = src[e];
  float* dst = agg + (long long)s * D_EDGE + q;
  atomicAdd(dst + 0, v.x);
  atomicAdd(dst + 1, v.y);
  atomicAdd(dst + 2, v.z);
  atomicAdd(dst + 3, v.w);
}

// 32 nodes per block, 256 threads.
// Phase 1: H[32][512] = silu(X @ W1 + b1); thread t owns hidden cols (t, t+256).
// Phase 2: Y[32][128] = H @ W2 + b2 via LDS transpose in 4 chunks of 128 cols;
//          thread t owns output col (t&127) for 16 nodes (group t>>7).
// Then LayerNorm + gamma/beta + residual.
__global__ __launch_bounds__(256) void mlp_ln_kernel(
    const float* __restrict__ nodef,
    const float* __restrict__ agg,
    const float* __restrict__ W1,
    const float* __restrict__ b1,
    const float* __restrict__ W2,
    const float* __restrict__ b2,
    const float* __restrict__ gamma,
    const float* __restrict__ beta,
    float* __restrict__ out) {
  __shared__ __align__(16) float xs[32][64];    // X K-chunk
  __shared__ __align__(16) float hs[32][128];   // H col-chunk, reused for Y
  __shared__ float mu_s[32];
  __shared__ float rs_s[32];

  const int t = threadIdx.x;
  const int node0 = blockIdx.x * 32;
  const int j0 = t;
  const int j1 = t + 256;

  float acc0[32], acc1[32];
  {
    const float bb0 = b1[j0];
    const float bb1 = b1[j1];
#pragma unroll
    for (int m = 0; m < 32; ++m) { acc0[m] = bb0; acc1[m] = bb1; }
  }

  // ---------------- layer 1: X = [node | agg], K = 256 in 4 chunks of 64 ----
  for (int kc = 0; kc < 4; ++kc) {
    {
      const int r = t >> 3;          // 0..31
      const int c = (t & 7) * 8;     // 0..56
      const float* base = (kc < 2)
          ? (nodef + (long long)(node0 + r) * D_NODE + kc * 64)
          : (agg   + (long long)(node0 + r) * D_EDGE + (kc - 2) * 64);
      const float4 v0 = *reinterpret_cast<const float4*>(base + c);
      const float4 v1 = *reinterpret_cast<const float4*>(base + c + 4);
      *reinterpret_cast<float4*>(&xs[r][c])     = v0;
      *reinterpret_cast<float4*>(&xs[r][c + 4]) = v1;
    }
    __syncthreads();
    const float* w1p = W1 + (long long)(kc * 64) * D_HID;
#pragma unroll 2
    for (int i = 0; i < 64; i += 4) {
      const float wa0 = w1p[(i + 0) * D_HID + j0];
      const float wa1 = w1p[(i + 1) * D_HID + j0];
      const float wa2 = w1p[(i + 2) * D_HID + j0];
      const float wa3 = w1p[(i + 3) * D_HID + j0];
      const float wb0 = w1p[(i + 0) * D_HID + j1];
      const float wb1 = w1p[(i + 1) * D_HID + j1];
      const float wb2 = w1p[(i + 2) * D_HID + j1];
      const float wb3 = w1p[(i + 3) * D_HID + j1];
#pragma unroll
      for (int m = 0; m < 32; ++m) {
        const float4 xv = *reinterpret_cast<const float4*>(&xs[m][i]); // broadcast
        acc0[m] = fmaf(xv.x, wa0, acc0[m]);
        acc0[m] = fmaf(xv.y, wa1, acc0[m]);
        acc0[m] = fmaf(xv.z, wa2, acc0[m]);
        acc0[m] = fmaf(xv.w, wa3, acc0[m]);
        acc1[m] = fmaf(xv.x, wb0, acc1[m]);
        acc1[m] = fmaf(xv.y, wb1, acc1[m]);
        acc1[m] = fmaf(xv.z, wb2, acc1[m]);
        acc1[m] = fmaf(xv.w, wb3, acc1[m]);
      }
    }
    __syncthreads();
  }

  // silu
#pragma unroll
  for (int m = 0; m < 32; ++m) {
    acc0[m] = __fdividef(acc0[m], 1.f + __expf(-acc0[m]));
    acc1[m] = __fdividef(acc1[m], 1.f + __expf(-acc1[m]));
  }

  // ---------------- layer 2: Y = H @ W2 + b2 -------------------------------
  const int c = t & 127;
  const int g = t >> 7;   // node group: 0 -> rows 0..15, 1 -> rows 16..31
  float acc2[16];
  {
    const float bb2 = b2[c];
#pragma unroll
    for (int m = 0; m < 16; ++m) acc2[m] = bb2;
  }

#pragma unroll
  for (int jc = 0; jc < 4; ++jc) {
    // chunk jc covers global hidden cols [jc*128, jc*128+128)
    if (g == (jc & 1)) {
#pragma unroll
      for (int m = 0; m < 32; ++m) hs[m][c] = (jc < 2) ? acc0[m] : acc1[m];
    }
    __syncthreads();
    const float* w2p = W2 + (long long)(jc * 128) * D_OUT;
#pragma unroll 2
    for (int j = 0; j < 128; j += 4) {
      const float w0  = w2p[(j + 0) * D_OUT + c];
      const float w1  = w2p[(j + 1) * D_OUT + c];
      const float w2v = w2p[(j + 2) * D_OUT + c];
      const float w3  = w2p[(j + 3) * D_OUT + c];
#pragma unroll
      for (int m = 0; m < 16; ++m) {
        const float4 hv = *reinterpret_cast<const float4*>(&hs[g * 16 + m][j]); // broadcast
        acc2[m] = fmaf(hv.x, w0,  acc2[m]);
        acc2[m] = fmaf(hv.y, w1,  acc2[m]);
        acc2[m] = fmaf(hv.z, w2v, acc2[m]);
        acc2[m] = fmaf(hv.w, w3,  acc2[m]);
      }
    }
    __syncthreads();
  }

  // ---------------- layernorm + residual -----------------------------------
#pragma unroll
  for (int m = 0; m < 16; ++m) hs[g * 16 + m][c] = acc2[m];
  __syncthreads();
  {
    const int r = t >> 3;   // 0..31
    const int k = t & 7;
    float s = 0.f, s2 = 0.f;
#pragma unroll
    for (int u = 0; u < 16; ++u) {
      const float v = hs[r][k + u * 8];
      s  += v;
      s2 += v * v;
    }
#pragma unroll
    for (int off = 1; off < 8; off <<= 1) {
      s  += __shfl_xor(s, off);
      s2 += __shfl_xor(s2, off);
    }
    if (k == 0) {
      const float mu  = s * (1.f / 128.f);
      const float var = s2 * (1.f / 128.f) - mu * mu;
      mu_s[r] = mu;
      rs_s[r] = rsqrtf(var + 1e-5f);
    }
  }
  __syncthreads();
  {
    const float gm = gamma[c];
    const float bt = beta[c];
#pragma unroll
    for (int m = 0; m < 16; ++m) {
      const int r = g * 16 + m;
      const long long n = node0 + r;
      const float y = (acc2[m] - mu_s[r]) * rs_s[r] * gm + bt
                      + nodef[n * D_NODE + c];
      out[n * D_OUT + c] = y;
    }
  }
}

} // namespace

extern "C" void kernel_launch(void* const* d_in, const int* in_sizes, int n_in,
                              void* d_out, int out_size, void* d_ws, size_t ws_size,
                              hipStream_t stream) {
  const float* nodef = (const float*)d_in[0];
  const float* ef    = (const float*)d_in[1];
  const float* W1    = (const float*)d_in[2];
  const float* b1    = (const float*)d_in[3];
  const float* W2    = (const float*)d_in[4];
  const float* b2    = (const float*)d_in[5];
  const float* gamma = (const float*)d_in[6];
  const float* beta  = (const float*)d_in[7];
  const int*   src   = (const int*)d_in[8];
  float* out = (float*)d_out;
  float* agg = (float*)d_ws;   // N_NODES * 128 f32 = 51.2 MB scratch

  hipMemsetAsync(agg, 0, (size_t)N_NODES * D_EDGE * sizeof(float), stream);

  {
    const long long total = (long long)N_EDGES * 32;  // (edge, float4) items
    const int block = 256;
    const int grid = (int)((total + block - 1) / block);  // 75000
    scatter_add_kernel<<<grid, block, 0, stream>>>(ef, src, agg);
  }

  mlp_ln_kernel<<<N_NODES / 32, 256, 0, stream>>>(
      nodef, agg, W1, b1, W2, b2, gamma, beta, out);
}